// Round 8
// baseline (356.981 us; speedup 1.0000x reference)
//
#include <hip/hip_runtime.h>
#include <hip/hip_bf16.h>

#define NN 100000
#define EE 500000
#define DD 128
#define NDEPTH 2
#define EPSV 1e-5f
#define NCHUNK 1024
#define NBLK ((NN + NCHUNK - 1) / NCHUNK)   // 98
#define NAB 6250     // aggbn blocks (x16 nodes = 100000)

typedef __attribute__((ext_vector_type(4))) float f32x4;
typedef __attribute__((ext_vector_type(4))) int i32x4;
typedef __attribute__((ext_vector_type(8))) short bf16x8;
typedef __attribute__((ext_vector_type(4))) short bf16x4;

static __device__ __forceinline__ short f2bf(float x) {
  union { float f; unsigned u; } v; v.f = x;
  unsigned r = v.u + 0x7fffu + ((v.u >> 16) & 1u);  // round-to-nearest-even
  return (short)(r >> 16);
}
static __device__ __forceinline__ float bfbits2f(unsigned hi16) {
  union { unsigned u; float f; } v; v.u = hi16;
  return v.f;
}

// ---- convert both weight tensors to bf16 once ----
__global__ void k_convert_w(const float* __restrict__ lw, const float* __restrict__ gw,
                            short* __restrict__ wbf) {
  int i = blockIdx.x * 256 + threadIdx.x;
  if (i < NDEPTH * DD * DD) {
    wbf[i] = f2bf(lw[i]);
    wbf[NDEPTH * DD * DD + i] = f2bf(gw[i]);
  }
}

// ---- edge pass 1: degree (weighted) + count histogram by col ----
__global__ void k_edge1(const int* __restrict__ ei, const float* __restrict__ ew,
                        float* __restrict__ deg, int* __restrict__ cnt) {
  int e = blockIdx.x * 256 + threadIdx.x;
  if (e < EE) {
    int c = ei[EE + e];
    atomicAdd(deg + c, ew[e]);
    atomicAdd(cnt + c, 1);
  }
}

__global__ void k_dinv(const float* __restrict__ deg, float* __restrict__ dinv) {
  int i = blockIdx.x * 256 + threadIdx.x;
  if (i < NN) {
    float d = deg[i];
    dinv[i] = d > 0.f ? rsqrtf(d) : 0.f;
  }
}

// ---- scan stage 1: per-chunk (1024 elems) sums ----
__global__ __launch_bounds__(256) void k_scan_part(const int* __restrict__ cnt,
                                                   int* __restrict__ part) {
  int b = blockIdx.x, t = threadIdx.x, lane = t & 63, wid = t >> 6;
  int base = b * NCHUNK + t * 4;
  int s = 0;
  if (base + 3 < NN) {
    i32x4 v = *(const i32x4*)(cnt + base);
    s = v[0] + v[1] + v[2] + v[3];
  } else {
    for (int j = 0; j < 4; ++j) if (base + j < NN) s += cnt[base + j];
  }
  for (int d = 32; d > 0; d >>= 1) s += __shfl_down(s, d);
  __shared__ int wsum[4];
  if (lane == 0) wsum[wid] = s;
  __syncthreads();
  if (t == 0) part[b] = wsum[0] + wsum[1] + wsum[2] + wsum[3];
}

// ---- scan stage 2: exclusive scan of the 98 partials ----
__global__ void k_scan_mid(int* __restrict__ part, int* __restrict__ rowptr) {
  __shared__ int sm[128];
  int t = threadIdx.x;
  int v = (t < NBLK) ? part[t] : 0;
  sm[t] = v;
  __syncthreads();
  for (int off = 1; off < 128; off <<= 1) {
    int a = sm[t];
    int b = (t >= off) ? sm[t - off] : 0;
    __syncthreads();
    sm[t] = a + b;
    __syncthreads();
  }
  if (t < NBLK) part[t] = (t == 0) ? 0 : sm[t - 1];
  if (t == 127) rowptr[NN] = sm[127];
}

// ---- scan stage 3: per-chunk exclusive scan -> rowptr, cursor ----
__global__ __launch_bounds__(256) void k_scan_final(const int* __restrict__ cnt,
    const int* __restrict__ part, int* __restrict__ rowptr, int* __restrict__ cursor) {
  int b = blockIdx.x, t = threadIdx.x, lane = t & 63, wid = t >> 6;
  int base = b * NCHUNK + t * 4;
  int c0 = 0, c1 = 0, c2 = 0, c3 = 0;
  if (base + 3 < NN) {
    i32x4 v = *(const i32x4*)(cnt + base);
    c0 = v[0]; c1 = v[1]; c2 = v[2]; c3 = v[3];
  } else {
    if (base < NN) c0 = cnt[base];
    if (base + 1 < NN) c1 = cnt[base + 1];
    if (base + 2 < NN) c2 = cnt[base + 2];
    if (base + 3 < NN) c3 = cnt[base + 3];
  }
  int s = c0 + c1 + c2 + c3;
  int v = s;
  for (int d = 1; d < 64; d <<= 1) {
    int u = __shfl_up(v, d);
    if (lane >= d) v += u;
  }
  __shared__ int wsum[4];
  if (lane == 63) wsum[wid] = v;
  __syncthreads();
  int woff = 0;
  for (int w = 0; w < wid; ++w) woff += wsum[w];
  int excl = part[b] + woff + (v - s);
  if (base < NN)     { rowptr[base]     = excl; cursor[base]     = excl; excl += c0; }
  if (base + 1 < NN) { rowptr[base + 1] = excl; cursor[base + 1] = excl; excl += c1; }
  if (base + 2 < NN) { rowptr[base + 2] = excl; cursor[base + 2] = excl; excl += c2; }
  if (base + 3 < NN) { rowptr[base + 3] = excl; cursor[base + 3] = excl; }
}

// ---- edge pass 2: bucket (row, norm) by col ----
__global__ void k_edge2(const int* __restrict__ ei, const float* __restrict__ ew,
                        const float* __restrict__ dinv, int* __restrict__ cursor,
                        int* __restrict__ srow, float* __restrict__ snorm) {
  int e = blockIdx.x * 256 + threadIdx.x;
  if (e < EE) {
    int r = ei[e], c = ei[EE + e];
    float nrm = dinv[r] * ew[e] * dinv[c];
    int pos = atomicAdd(cursor + c, 1);
    srow[pos] = r;
    snorm[pos] = nrm;
  }
}

// ---- dual GEMM with LDS-staged weights. 512 threads = 8 waves x 16 rows = 128 rows/block.
// LDS: Wl (32KB) + Wg (32KB), rows of 256B, 16B-units XOR-swizzled by (row&7).
// Swapped-operand MFMA: mfma(first=W, second=H) -> lane m=lane&15 is node row,
// acc idx i is channel t*16 + g*4 + i (g=lane>>4) -> f32x4 store per row.
// APPLY=1: input is pre-BN h; apply per-column scale/bias + ReLU before bf16 convert
// (bit-identical to the former separate bnapply pass).
template<int APPLY>
__global__ __launch_bounds__(512) void k_dualgemm(const float* __restrict__ H,
    const short* __restrict__ Wl, const short* __restrict__ Wg,
    const float* __restrict__ sb, float* __restrict__ tmp, unsigned short* __restrict__ hg) {
  __shared__ short lw[2 * DD * DD];   // 64 KB
  int tid = threadIdx.x;

  // stage: 4096 16B-units; swizzled global source -> linear LDS
#pragma unroll
  for (int c = 0; c < 8; ++c) {
    int q = c * 512 + tid;
    int region = q >> 11;            // 0 = Wl, 1 = Wg
    int row = (q >> 4) & 127;
    int u = q & 15;
    const short* src = (region ? Wg : Wl) + row * DD + ((u ^ (row & 7)) * 8);
    *(bf16x8*)(lw + q * 8) = *(const bf16x8*)src;
  }

  int lane = tid & 63, wv = tid >> 6;
  int row0 = blockIdx.x * 128 + wv * 16;
  int m = lane & 15, g = lane >> 4;

  bf16x8 hb[4];
  if (row0 < NN) {
    const float* hrow = H + (size_t)(row0 + m) * DD + g * 8;
#pragma unroll
    for (int s = 0; s < 4; ++s) {
      f32x4 v0 = *(const f32x4*)(hrow + s * 32);
      f32x4 v1 = *(const f32x4*)(hrow + s * 32 + 4);
      if (APPLY) {
        f32x4 sc0 = *(const f32x4*)(sb + s * 32 + g * 8);
        f32x4 sc1 = *(const f32x4*)(sb + s * 32 + g * 8 + 4);
        f32x4 bi0 = *(const f32x4*)(sb + DD + s * 32 + g * 8);
        f32x4 bi1 = *(const f32x4*)(sb + DD + s * 32 + g * 8 + 4);
#pragma unroll
        for (int k2 = 0; k2 < 4; ++k2) {
          v0[k2] = fmaxf(v0[k2] * sc0[k2] + bi0[k2], 0.f);
          v1[k2] = fmaxf(v1[k2] * sc1[k2] + bi1[k2], 0.f);
        }
      }
      bf16x8 tt;
      tt[0] = f2bf(v0[0]); tt[1] = f2bf(v0[1]); tt[2] = f2bf(v0[2]); tt[3] = f2bf(v0[3]);
      tt[4] = f2bf(v1[0]); tt[5] = f2bf(v1[1]); tt[6] = f2bf(v1[2]); tt[7] = f2bf(v1[3]);
      hb[s] = tt;
    }
  }

  __syncthreads();
  if (row0 >= NN) return;

  int mx = m & 7;
#pragma unroll
  for (int t = 0; t < 8; ++t) {
    f32x4 accl; accl[0] = 0.f; accl[1] = 0.f; accl[2] = 0.f; accl[3] = 0.f;
    f32x4 accg = accl;
#pragma unroll
    for (int s = 0; s < 4; ++s) {
      int u = (s * 4 + g) ^ mx;
      int base = (t * 16 + m) * DD + u * 8;
      bf16x8 wlf = *(const bf16x8*)(lw + base);
      bf16x8 wgf = *(const bf16x8*)(lw + 2 * DD * DD / 2 + base);  // +16384 shorts
      accl = __builtin_amdgcn_mfma_f32_16x16x32_bf16(wlf, hb[s], accl, 0, 0, 0);
      accg = __builtin_amdgcn_mfma_f32_16x16x32_bf16(wgf, hb[s], accg, 0, 0, 0);
    }
    size_t r = (size_t)(row0 + m);
    *(f32x4*)(tmp + r * DD + t * 16 + g * 4) = accl;
    bf16x4 h4;
    h4[0] = f2bf(accg[0]); h4[1] = f2bf(accg[1]);
    h4[2] = f2bf(accg[2]); h4[3] = f2bf(accg[3]);
    *(bf16x4*)(hg + r * DD + t * 16 + g * 4) = h4;
  }
}

// ---- fused aggregation + BN stats: block = 4 waves x 4 nodes = 16 nodes.
// tmp[node] += sum norm * hg[srcrow]; accumulate column sum/sumsq of final h
// into per-block partials (psum/pss [block][128]).
__global__ __launch_bounds__(256) void k_aggbn(const int* __restrict__ rowptr,
    const int* __restrict__ srow, const float* __restrict__ snorm,
    const unsigned int* __restrict__ hgu, float* __restrict__ tmp,
    float* __restrict__ psum, float* __restrict__ pss) {
  int tid = threadIdx.x, lane = tid & 63, wv = tid >> 6;
  int b = blockIdx.x;
  float s0 = 0.f, s1 = 0.f, q0 = 0.f, q1 = 0.f;
#pragma unroll
  for (int n = 0; n < 4; ++n) {
    int node = b * 16 + wv * 4 + n;   // NAB*16 == NN exactly
    int beg = rowptr[node], end = rowptr[node + 1];
    float ax = 0.f, ay = 0.f;
    for (int j = beg; j < end; ++j) {
      int r = srow[j];
      float w = snorm[j];
      unsigned u = hgu[r * 64 + lane];      // 2 bf16: cols 2*lane, 2*lane+1
      ax += w * bfbits2f(u << 16);
      ay += w * bfbits2f(u & 0xffff0000u);
    }
    float* tp = tmp + (size_t)node * DD + lane * 2;
    float t0 = tp[0] + ax, t1 = tp[1] + ay;
    tp[0] = t0; tp[1] = t1;
    s0 += t0; s1 += t1; q0 += t0 * t0; q1 += t1 * t1;
  }
  __shared__ float red[4][256];
  f32x4 pk; pk[0] = s0; pk[1] = s1; pk[2] = q0; pk[3] = q1;
  *(f32x4*)&red[wv][lane * 4] = pk;
  __syncthreads();
  float v = red[0][tid] + red[1][tid] + red[2][tid] + red[3][tid];
  int col = (tid >> 2) * 2 + (tid & 1);
  if (((tid >> 1) & 1) == 0) psum[(size_t)b * DD + col] = v;
  else                       pss [(size_t)b * DD + col] = v;
}

// ---- reduce partials -> per-column scale/bias (folds gamma/beta/rsqrt) ----
__global__ __launch_bounds__(256) void k_bnreduce(const float* __restrict__ psum,
    const float* __restrict__ pss, const float* __restrict__ gamma,
    const float* __restrict__ beta, float* __restrict__ sb) {
  int col = blockIdx.x, t = threadIdx.x;
  float s = 0.f, q = 0.f;
  for (int i = t; i < NAB; i += 256) {
    s += psum[(size_t)i * DD + col];
    q += pss[(size_t)i * DD + col];
  }
  for (int d = 32; d > 0; d >>= 1) { s += __shfl_down(s, d); q += __shfl_down(q, d); }
  __shared__ float lws[4], lwq[4];
  int wid = t >> 6, lane = t & 63;
  if (lane == 0) { lws[wid] = s; lwq[wid] = q; }
  __syncthreads();
  if (t == 0) {
    float S = lws[0] + lws[1] + lws[2] + lws[3];
    float Q = lwq[0] + lwq[1] + lwq[2] + lwq[3];
    float mean = S * (1.f / NN);
    float var = Q * (1.f / NN) - mean * mean;
    float sc = rsqrtf(var + EPSV) * gamma[col];
    sb[col] = sc;
    sb[DD + col] = beta[col] - mean * sc;
  }
}

// ---- BN apply (final layer only, in-place, no relu): x*scale + bias ----
__global__ void k_bnapply(const float* __restrict__ h, const float* __restrict__ sb,
                          float* __restrict__ out, int relu) {
  int i = blockIdx.x * 256 + threadIdx.x;
  if (i >= NN * DD / 4) return;
  int d0 = (i * 4) & (DD - 1);
  f32x4 v = ((const f32x4*)h)[i];
  f32x4 o;
#pragma unroll
  for (int c = 0; c < 4; ++c) {
    float x = v[c] * sb[d0 + c] + sb[DD + d0 + c];
    o[c] = relu ? fmaxf(x, 0.f) : x;
  }
  ((f32x4*)out)[i] = o;
}

extern "C" void kernel_launch(void* const* d_in, const int* in_sizes, int n_in,
                              void* d_out, int out_size, void* d_ws, size_t ws_size,
                              hipStream_t stream) {
  const float* x     = (const float*)d_in[0];
  const int*   ei    = (const int*)d_in[1];
  const float* ew    = (const float*)d_in[2];
  const float* lin_w = (const float*)d_in[3];
  const float* gcn_w = (const float*)d_in[4];
  const float* gamma = (const float*)d_in[5];
  const float* beta  = (const float*)d_in[6];
  float* out = (float*)d_out;

  char* ws = (char*)d_ws;
  size_t off = 0;
  auto alloc = [&](size_t bytes) -> void* {
    void* p = ws + off;
    off += (bytes + 255) & ~(size_t)255;
    return p;
  };
  unsigned short* hg = (unsigned short*)alloc((size_t)NN * DD * 2);  // bf16
  float* tmp    = (float*)alloc((size_t)NN * DD * 4);
  float* snorm  = (float*)alloc((size_t)EE * 4);
  int*   srow   = (int*)alloc((size_t)EE * 4);
  float* deg    = (float*)alloc((size_t)NN * 4);
  float* dinv   = (float*)alloc((size_t)NN * 4);
  int*   rowptr = (int*)alloc((size_t)(NN + 1) * 4);
  int*   cursor = (int*)alloc((size_t)NN * 4);
  int*   cnt    = (int*)alloc((size_t)NN * 4);
  int*   part   = (int*)alloc((size_t)NBLK * 4);
  short* wbf    = (short*)alloc((size_t)2 * NDEPTH * DD * DD * 2);
  float* psum   = (float*)alloc((size_t)NAB * DD * 4);
  float* pss    = (float*)alloc((size_t)NAB * DD * 4);
  float* sb     = (float*)alloc((size_t)2 * DD * 4);

  hipMemsetAsync(deg, 0, (size_t)NN * 4, stream);
  hipMemsetAsync(cnt, 0, (size_t)NN * 4, stream);

  k_convert_w<<<(NDEPTH * DD * DD + 255) / 256, 256, 0, stream>>>(lin_w, gcn_w, wbf);
  k_edge1<<<(EE + 255) / 256, 256, 0, stream>>>(ei, ew, deg, cnt);
  k_dinv<<<(NN + 255) / 256, 256, 0, stream>>>(deg, dinv);
  k_scan_part<<<NBLK, 256, 0, stream>>>(cnt, part);
  k_scan_mid<<<1, 128, 0, stream>>>(part, rowptr);
  k_scan_final<<<NBLK, 256, 0, stream>>>(cnt, part, rowptr, cursor);
  k_edge2<<<(EE + 255) / 256, 256, 0, stream>>>(ei, ew, dinv, cursor, srow, snorm);

  const short* Wl0 = wbf;
  const short* Wg0 = wbf + (size_t)NDEPTH * DD * DD;
  const short* Wl1 = wbf + (size_t)DD * DD;
  const short* Wg1 = wbf + (size_t)NDEPTH * DD * DD + (size_t)DD * DD;
  const int GEMMBLK = (NN + 127) / 128;   // 782

  // layer 0: tmp = x@Wl0^T (f32), hg = x@Wg0^T (bf16); agg+stats; sb0
  k_dualgemm<0><<<GEMMBLK, 512, 0, stream>>>(x, Wl0, Wg0, sb, tmp, hg);
  k_aggbn<<<NAB, 256, 0, stream>>>(rowptr, srow, snorm, (const unsigned int*)hg, tmp, psum, pss);
  k_bnreduce<<<DD, 256, 0, stream>>>(psum, pss, gamma, beta, sb);

  // layer 1: BN+ReLU folded into the GEMM's H load; hl -> out; agg+stats; sb1; final BN in-place
  k_dualgemm<1><<<GEMMBLK, 512, 0, stream>>>(tmp, Wl1, Wg1, sb, out, hg);
  k_aggbn<<<NAB, 256, 0, stream>>>(rowptr, srow, snorm, (const unsigned int*)hg, out, psum, pss);
  k_bnreduce<<<DD, 256, 0, stream>>>(psum, pss, gamma + DD, beta + DD, sb);
  k_bnapply<<<(NN * DD / 4 + 255) / 256, 256, 0, stream>>>(out, sb, out, 0);
}